// Round 1
// 233.957 us; speedup vs baseline: 1.0094x; 1.0094x over previous
//
#include <hip/hip_runtime.h>

#define EPS 1e-6f

typedef short s8v __attribute__((ext_vector_type(8)));
typedef float f4v __attribute__((ext_vector_type(4)));

__device__ __forceinline__ unsigned short f2bf(float f) {
    unsigned u = __float_as_uint(f);
    u += 0x7FFFu + ((u >> 16) & 1u);   // RTNE
    return (unsigned short)(u >> 16);
}

// split x ~= hi + lo (both bf16); residual <= 2^-17 |x|
__device__ __forceinline__ void split2(float a, float b, unsigned& h, unsigned& l) {
    unsigned short ha = f2bf(a), hb = f2bf(b);
    float ra = a - __uint_as_float((unsigned)ha << 16);
    float rb = b - __uint_as_float((unsigned)hb << 16);
    h = (unsigned)ha | ((unsigned)hb << 16);
    l = (unsigned)f2bf(ra) | ((unsigned)f2bf(rb) << 16);
}

// 16B-aligned LDS fragment load -> single ds_read_b128
__device__ __forceinline__ s8v ld16(const unsigned short* p) {
    return *(const s8v*)p;
}

__device__ __forceinline__ double shfl_xor_dbl(double x, int msk) {
    long long l = __double_as_longlong(x);
    int lo = (int)(l & 0xffffffffll), hi = (int)(l >> 32);
    lo = __shfl_xor(lo, msk, 64);
    hi = __shfl_xor(hi, msk, 64);
    return __longlong_as_double(((long long)hi << 32) | (unsigned)lo);
}

// Phase-1 LDS layout: 64 rows x 136 ushorts (row stride 272B = 17*16B).
// Column 16B-quads additively swizzled by row/2: reads (ds_read_b128) land
// 8 lanes per bank-quad (conflict-free optimum); stores stay 4-way.
__device__ __forceinline__ int swzA(int row, int s) {
    return row * 136 + ((((s >> 3) + (row >> 1)) & 15) << 3) + (s & 7);
}
// Phase-2 LDS layout: 64 rows x 72 ushorts (row stride 144B = 9*16B), 8 quads.
__device__ __forceinline__ int swzB(int row, int s) {
    return row * 72 + ((((s >> 3) + (row >> 1)) & 7) << 3) + (s & 7);
}

// ---------------- Phase 1: partial M (split-bf16 MFMA) + partial z (fp64) ----------------
// grid (8 chunks, 64 heads), 512 threads (8 waves). chunk = 512 s-rows, 4 stages of 128.
// LDS 73.7 KB -> 2 blocks/CU x 8 waves = 16 waves/CU (4/SIMD); all 512 blocks resident.
// Stage st+1's global loads issue BEFORE stage st's barriers/MFMA (latency hidden).
__global__ __launch_bounds__(512, 4) void mm_phase1(const float* __restrict__ Kg,
                                                    const float* __restrict__ Vg,
                                                    float* __restrict__ partM,
                                                    double* __restrict__ partZ) {
    __shared__ __align__(16) unsigned short Kh[64 * 136], Kl[64 * 136];
    __shared__ __align__(16) unsigned short Vh[64 * 136], Vl[64 * 136];
    __shared__ double zsw[8][16][4];

    const int chunk = blockIdx.x;
    const int head  = blockIdx.y;
    const int t = threadIdx.x;
    const int lane = t & 63;
    const int w = t >> 6;
    const int dg = (t & 15) * 4;       // d-column group (LDS rows)
    const int sg = (t >> 4) * 4;       // s-row group 0..124 (LDS cols)
    const int m = lane & 15, q = lane >> 4;
    const int rt_ = w >> 1, ch = w & 1; // wave's M row-tile / col-half

    const long hbase = (long)head * 4096 * 64;
    const int srow0 = chunk * 512;

    f4v acc[2];
    acc[0] = (f4v){0.f, 0.f, 0.f, 0.f};
    acc[1] = (f4v){0.f, 0.f, 0.f, 0.f};
    double z4[4] = {0.0, 0.0, 0.0, 0.0};

    auto load_stage = [&](int st, float4* kr, float4* vr) {
#pragma unroll
        for (int i = 0; i < 4; ++i) {
            const long off = hbase + (long)(srow0 + st * 128 + sg + i) * 64 + dg;
            kr[i] = *(const float4*)(Kg + off);
            vr[i] = *(const float4*)(Vg + off);
        }
    };

    float4 kr[4], vr[4];
    load_stage(0, kr, vr);

#pragma unroll
    for (int st = 0; st < 4; ++st) {
        // prefetch next stage early: overlaps barrier wait + split + MFMA below
        float4 nk[4], nv[4];
        if (st < 3) load_stage(st + 1, nk, nv);
        __syncthreads();   // prev-stage MFMA readers done
        // z accumulation (fp64, per-thread columns dg..dg+3)
#pragma unroll
        for (int i = 0; i < 4; ++i) {
            z4[0] += (double)kr[i].x; z4[1] += (double)kr[i].y;
            z4[2] += (double)kr[i].z; z4[3] += (double)kr[i].w;
        }
        // split + transpose-store to LDS (swizzled)
#pragma unroll
        for (int j = 0; j < 4; ++j) {
            const int o = swzA(dg + j, sg);
            uint2 ph, pl;
            split2((&kr[0].x)[j], (&kr[1].x)[j], ph.x, pl.x);
            split2((&kr[2].x)[j], (&kr[3].x)[j], ph.y, pl.y);
            *(uint2*)&Kh[o] = ph;
            *(uint2*)&Kl[o] = pl;
            split2((&vr[0].x)[j], (&vr[1].x)[j], ph.x, pl.x);
            split2((&vr[2].x)[j], (&vr[3].x)[j], ph.y, pl.y);
            *(uint2*)&Vh[o] = ph;
            *(uint2*)&Vl[o] = pl;
        }
        __syncthreads();
        // MFMA: wave owns M rows [rt_*16, rt_*16+16), cols [ch*32, ch*32+32)
        const int arow = rt_ * 16 + m;
#pragma unroll
        for (int ks = 0; ks < 4; ++ks) {
            const int k0 = ks * 32 + q * 8;
            s8v ahf = ld16(&Kh[swzA(arow, k0)]);
            s8v alf = ld16(&Kl[swzA(arow, k0)]);
#pragma unroll
            for (int c = 0; c < 2; ++c) {
                const int vrow = (ch * 2 + c) * 16 + m;
                s8v bh = ld16(&Vh[swzA(vrow, k0)]);
                s8v bl = ld16(&Vl[swzA(vrow, k0)]);
                acc[c] = __builtin_amdgcn_mfma_f32_16x16x32_bf16(ahf, bh, acc[c], 0, 0, 0);
                acc[c] = __builtin_amdgcn_mfma_f32_16x16x32_bf16(ahf, bl, acc[c], 0, 0, 0);
                acc[c] = __builtin_amdgcn_mfma_f32_16x16x32_bf16(alf, bh, acc[c], 0, 0, 0);
            }
        }
        if (st < 3) {
#pragma unroll
            for (int i = 0; i < 4; ++i) { kr[i] = nk[i]; vr[i] = nv[i]; }
        }
    }

    // write partial M (C layout: col=lane&15, row=(lane>>4)*4+reg)
    float* pm = partM + ((long)(head * 8 + chunk) << 12);
#pragma unroll
    for (int c = 0; c < 2; ++c)
#pragma unroll
        for (int r2 = 0; r2 < 4; ++r2)
            pm[(rt_ * 16 + q * 4 + r2) * 64 + (ch * 2 + c) * 16 + m] = acc[c][r2];

    // z: butterfly over the 4 lanes sharing m, then cross-wave via 4KB LDS
#pragma unroll
    for (int cc = 0; cc < 4; ++cc) {
        z4[cc] += shfl_xor_dbl(z4[cc], 16);
        z4[cc] += shfl_xor_dbl(z4[cc], 32);
    }
    if (lane < 16) {
#pragma unroll
        for (int cc = 0; cc < 4; ++cc) zsw[w][lane][cc] = z4[cc];
    }
    __syncthreads();
    if (t < 64) {
        double s = 0.0;
#pragma unroll
        for (int g = 0; g < 8; ++g) s += zsw[g][t >> 2][t & 3];
        partZ[(head * 8 + chunk) * 64 + t] = s;
    }
}

// ---------------- Reduce: sum chunks -> Mt fp32 (transposed) + z fp64 ----------------
// grid (4 k-slices, 64 heads): each block handles 16 of the 64 k-rows of one head.
__global__ __launch_bounds__(256) void mm_reduce(const float* __restrict__ partM,
                                                 const double* __restrict__ partZ,
                                                 float* __restrict__ MtG,
                                                 double* __restrict__ zf) {
    __shared__ float Ml[16][68];
    const int b = blockIdx.x, h = blockIdx.y, t = threadIdx.x;
#pragma unroll
    for (int it = 0; it < 4; ++it) {
        const int fl = it * 256 + t;          // 0..1023 within slice
        const int f = b * 1024 + fl;
        float s = 0.f;
#pragma unroll
        for (int c = 0; c < 8; ++c) s += partM[(long)(h * 8 + c) * 4096 + f];
        Ml[fl >> 6][fl & 63] = s;
    }
    if (b == 0 && t < 64) {
        double s = 0.0;
#pragma unroll
        for (int c = 0; c < 8; ++c) s += partZ[(h * 8 + c) * 64 + t];
        zf[h * 64 + t] = s;
    }
    __syncthreads();
    // Mt[n][k] = M[k][n]: thread t writes row n=t>>2, k-cols b*16 + (t&3)*4 .. +4
    const int n = t >> 2, kq = (t & 3) * 4;
    float4 o;
#pragma unroll
    for (int j = 0; j < 4; ++j) (&o.x)[j] = Ml[kq + j][n];
    *(float4*)(MtG + (long)h * 4096 + n * 64 + b * 16 + kq) = o;
}

// ---------------- Phase 2: out = (Q @ M) / (fp32 den) ----------------
// grid (32 s-blocks, 64 heads), 256 threads, 128 rows/block.
// den computed from the qa registers (the 4 lanes sharing m jointly hold a full
// Q row): fp64 butterfly + shfl redistribution — no Q re-read, no denS, 1 barrier.
__global__ __launch_bounds__(256, 4) void mm_phase2(const float* __restrict__ Qg,
                                                    const float* __restrict__ MtG,
                                                    const double* __restrict__ zf,
                                                    float* __restrict__ outg) {
    __shared__ __align__(16) unsigned short Mth[64 * 72], Mtl[64 * 72];
    __shared__ __align__(16) float zl[64];

    const int sb = blockIdx.x, h = blockIdx.y;
    const int t = threadIdx.x, lane = t & 63, w = t >> 6;
    const long hq = (long)h * 4096 * 64;
    const int s0 = sb * 128;
    const int m = lane & 15, q = lane >> 4;

    // ---- A-fragment loads first: pull the Q tile from HBM early ----
    // qa[0..1]=row0 k0..31, qa[2..3]=row0 k32..63, qa[4..7]=row1 (rt=1)
    float4 qa[8];
    {
        const float* qr0 = Qg + hq + (long)(s0 + w * 32 + m) * 64;
        const float* qr1 = qr0 + 16 * 64;
#pragma unroll
        for (int i = 0; i < 2; ++i) {
            qa[0 + i] = *(const float4*)(qr0 + q * 8 + 4 * i);
            qa[2 + i] = *(const float4*)(qr0 + 32 + q * 8 + 4 * i);
            qa[4 + i] = *(const float4*)(qr1 + q * 8 + 4 * i);
            qa[6 + i] = *(const float4*)(qr1 + 32 + q * 8 + 4 * i);
        }
    }

    // ---- stage Mt (fp32 -> split bf16 hi/lo, swizzled) + z (fp32) ----
    {
        const float* Msrc = MtG + (long)h * 4096;
        const int n = t >> 2, k0 = (t & 3) * 16;
#pragma unroll
        for (int i = 0; i < 4; ++i) {
            float4 v = *(const float4*)(Msrc + n * 64 + k0 + 4 * i);
            uint2 ph, pl;
            split2(v.x, v.y, ph.x, pl.x);
            split2(v.z, v.w, ph.y, pl.y);
            const int o = swzB(n, k0 + 4 * i);
            *(uint2*)&Mth[o] = ph;
            *(uint2*)&Mtl[o] = pl;
        }
        if (t < 64) zl[t] = (float)zf[h * 64 + t];
    }
    __syncthreads();

    // ---- den from registers: fp32-rounded products (no FMA), exact fp64 sum,
    // then fp32 + EPS — same numerics class as before (order-independent part
    // of np's fp32 dot), association differs only at fp64 epsilon.
    float dv[2][4];
    {
        float zq[16];
        *(float4*)&zq[0]  = *(const float4*)&zl[q * 8];
        *(float4*)&zq[4]  = *(const float4*)&zl[q * 8 + 4];
        *(float4*)&zq[8]  = *(const float4*)&zl[32 + q * 8];
        *(float4*)&zq[12] = *(const float4*)&zl[32 + q * 8 + 4];
        const float* qp0 = (const float*)&qa[0];
        const float* qp1 = (const float*)&qa[4];
        double dp0 = 0.0, dp1 = 0.0;
#pragma unroll
        for (int j = 0; j < 16; ++j) {
            dp0 += (double)__fmul_rn(qp0[j], zq[j]);
            dp1 += (double)__fmul_rn(qp1[j], zq[j]);
        }
        dp0 += shfl_xor_dbl(dp0, 16); dp0 += shfl_xor_dbl(dp0, 32);
        dp1 += shfl_xor_dbl(dp1, 16); dp1 += shfl_xor_dbl(dp1, 32);
        const float den0 = __fadd_rn((float)dp0, EPS);   // row w*32 + m
        const float den1 = __fadd_rn((float)dp1, EPS);   // row w*32 + 16 + m
        // redistribute: output rows are q*4+r2 (+16*rt); lane q*4+r2 holds them
#pragma unroll
        for (int r2 = 0; r2 < 4; ++r2) {
            dv[0][r2] = __shfl(den0, q * 4 + r2, 64);
            dv[1][r2] = __shfl(den1, q * 4 + r2, 64);
        }
    }

    // ---- A fragments (split bf16 hi/lo), both row-tiles ----
    union U8 { s8v v; unsigned u[4]; };
    U8 ah[2][2], al[2][2];
#pragma unroll
    for (int rt = 0; rt < 2; ++rt) {
        const float4* qq = &qa[rt * 4];
        split2(qq[0].x, qq[0].y, ah[rt][0].u[0], al[rt][0].u[0]);
        split2(qq[0].z, qq[0].w, ah[rt][0].u[1], al[rt][0].u[1]);
        split2(qq[1].x, qq[1].y, ah[rt][0].u[2], al[rt][0].u[2]);
        split2(qq[1].z, qq[1].w, ah[rt][0].u[3], al[rt][0].u[3]);
        split2(qq[2].x, qq[2].y, ah[rt][1].u[0], al[rt][1].u[0]);
        split2(qq[2].z, qq[2].w, ah[rt][1].u[1], al[rt][1].u[1]);
        split2(qq[3].x, qq[3].y, ah[rt][1].u[2], al[rt][1].u[2]);
        split2(qq[3].z, qq[3].w, ah[rt][1].u[3], al[rt][1].u[3]);
    }

    // ---- ct-outer / rt-inner: B fragments live only per-ct (VGPR relief) ----
#pragma unroll
    for (int ct = 0; ct < 4; ++ct) {
        const int brow = ct * 16 + m;
        s8v bh0 = ld16(&Mth[swzB(brow, q * 8)]);
        s8v bl0 = ld16(&Mtl[swzB(brow, q * 8)]);
        s8v bh1 = ld16(&Mth[swzB(brow, 32 + q * 8)]);
        s8v bl1 = ld16(&Mtl[swzB(brow, 32 + q * 8)]);
#pragma unroll
        for (int rt = 0; rt < 2; ++rt) {
            f4v acc = (f4v){0.f, 0.f, 0.f, 0.f};
            acc = __builtin_amdgcn_mfma_f32_16x16x32_bf16(ah[rt][0].v, bh0, acc, 0, 0, 0);
            acc = __builtin_amdgcn_mfma_f32_16x16x32_bf16(ah[rt][0].v, bl0, acc, 0, 0, 0);
            acc = __builtin_amdgcn_mfma_f32_16x16x32_bf16(al[rt][0].v, bh0, acc, 0, 0, 0);
            acc = __builtin_amdgcn_mfma_f32_16x16x32_bf16(ah[rt][1].v, bh1, acc, 0, 0, 0);
            acc = __builtin_amdgcn_mfma_f32_16x16x32_bf16(ah[rt][1].v, bl1, acc, 0, 0, 0);
            acc = __builtin_amdgcn_mfma_f32_16x16x32_bf16(al[rt][1].v, bh1, acc, 0, 0, 0);
            const long rb = hq + (long)(s0 + w * 32 + rt * 16 + q * 4) * 64 + ct * 16 + m;
#pragma unroll
            for (int r2 = 0; r2 < 4; ++r2)
                outg[rb + (long)r2 * 64] = __fdiv_rn(acc[r2], dv[rt][r2]);   // IEEE fp32 divide
        }
    }
}

extern "C" void kernel_launch(void* const* d_in, const int* in_sizes, int n_in,
                              void* d_out, int out_size, void* d_ws, size_t ws_size,
                              hipStream_t stream) {
    const float* K = (const float*)d_in[0];
    const float* V = (const float*)d_in[1];
    const float* Q = (const float*)d_in[2];
    float* out = (float*)d_out;

    char* ws = (char*)d_ws;
    float*  partM = (float*)ws;                      // 64*8*4096*4 = 8 MiB
    double* partZ = (double*)(ws + 8388608);         // 64*8*64*8   = 256 KiB
    float*  MtG   = (float*)(ws + 8650752);          // 64*4096*4   = 1 MiB
    double* zfin  = (double*)(ws + 9699328);         // 64*64*8     = 32 KiB

    mm_phase1<<<dim3(8, 64), 512, 0, stream>>>(K, V, partM, partZ);
    mm_reduce<<<dim3(4, 64), 256, 0, stream>>>(partM, partZ, MtG, zfin);
    mm_phase2<<<dim3(32, 64), 256, 0, stream>>>(Q, MtG, zfin, out);
}

// Round 2
// 231.614 us; speedup vs baseline: 1.0196x; 1.0101x over previous
//
#include <hip/hip_runtime.h>

#define EPS 1e-6f

typedef short s8v __attribute__((ext_vector_type(8)));
typedef float f4v __attribute__((ext_vector_type(4)));

__device__ __forceinline__ unsigned short f2bf(float f) {
    unsigned u = __float_as_uint(f);
    u += 0x7FFFu + ((u >> 16) & 1u);   // RTNE
    return (unsigned short)(u >> 16);
}

// split x ~= hi + lo (both bf16); residual <= 2^-17 |x|
__device__ __forceinline__ void split2(float a, float b, unsigned& h, unsigned& l) {
    unsigned short ha = f2bf(a), hb = f2bf(b);
    float ra = a - __uint_as_float((unsigned)ha << 16);
    float rb = b - __uint_as_float((unsigned)hb << 16);
    h = (unsigned)ha | ((unsigned)hb << 16);
    l = (unsigned)f2bf(ra) | ((unsigned)f2bf(rb) << 16);
}

__device__ __forceinline__ s8v ld16(const unsigned short* p) {
    return *(const s8v*)p;   // ds_read_b128 / global_load_dwordx4
}

__device__ __forceinline__ double shfl_xor_dbl(double x, int msk) {
    long long l = __double_as_longlong(x);
    int lo = (int)(l & 0xffffffffll), hi = (int)(l >> 32);
    lo = __shfl_xor(lo, msk, 64);
    hi = __shfl_xor(hi, msk, 64);
    return __longlong_as_double(((long long)hi << 32) | (unsigned)lo);
}

// Raw workgroup barrier: waits LDS ops only, does NOT drain vmcnt.
// (__syncthreads() emits s_waitcnt vmcnt(0) before s_barrier — that drain
// was serializing every stage; global loads may now stay in flight across.)
__device__ __forceinline__ void wg_barrier() {
    asm volatile("s_waitcnt lgkmcnt(0)\n\ts_barrier" ::: "memory");
}

// LDS layout: 64 rows x 72 ushorts (row stride 144B = 9*16B).
// 16B-quads additively swizzled by row>>1: ds_read_b128 fragment reads are
// conflict-free (m vs m+8 differ by 16 banks); stores ~4-way.
__device__ __forceinline__ int swz(int row, int s) {
    return row * 72 + ((((s >> 3) + (row >> 1)) & 7) << 3) + (s & 7);
}

// ---------------- Phase 1: partial M (split-bf16 MFMA) + partial z (fp64) ----------------
// grid (8 chunks, 64 heads), 512 threads (8 waves). chunk = 512 s-rows.
// 8 stages of 64 rows, LDS double-buffered (73.7 KB -> 2 blocks/CU, 16 waves/CU).
// Loads issued 2 stages ahead; ONE raw barrier per stage (no vmcnt drain).
__global__ __launch_bounds__(512, 4) void mm_phase1(const float* __restrict__ Kg,
                                                    const float* __restrict__ Vg,
                                                    float* __restrict__ partM,
                                                    double* __restrict__ partZ) {
    __shared__ __align__(16) unsigned short Kh[2][64 * 72], Kl[2][64 * 72];
    __shared__ __align__(16) unsigned short Vh[2][64 * 72], Vl[2][64 * 72];

    const int chunk = blockIdx.x;
    const int head  = blockIdx.y;
    const int t = threadIdx.x;
    const int lane = t & 63;
    const int w = t >> 6;
    const int dg = (t & 15) * 4;       // d-column group (LDS rows)
    const int sg = (t >> 4) * 2;       // s-row pair 0..62 (LDS cols)
    const int m = lane & 15, q = lane >> 4;
    const int rt_ = w >> 1, ch = w & 1; // wave's M row-tile / col-half

    const long hbase = (long)head * 4096 * 64;
    const int srow0 = chunk * 512;

    f4v acc[2];
    acc[0] = (f4v){0.f, 0.f, 0.f, 0.f};
    acc[1] = (f4v){0.f, 0.f, 0.f, 0.f};
    double z4[4] = {0.0, 0.0, 0.0, 0.0};

    float4 kb[3][2], vb[3][2];   // rotating 2-deep prefetch (static idx via unroll)
    auto load_stage = [&](int st, float4* kr, float4* vr) {
#pragma unroll
        for (int i = 0; i < 2; ++i) {
            const long off = hbase + (long)(srow0 + st * 64 + sg + i) * 64 + dg;
            kr[i] = *(const float4*)(Kg + off);
            vr[i] = *(const float4*)(Vg + off);
        }
    };
    load_stage(0, kb[0], vb[0]);
    load_stage(1, kb[1], vb[1]);

#pragma unroll
    for (int st = 0; st < 8; ++st) {
        if (st < 6) load_stage(st + 2, kb[(st + 2) % 3], vb[(st + 2) % 3]);
        const float4* kr = kb[st % 3];
        const float4* vr = vb[st % 3];
        const int bs = st & 1;
        // z accumulation (fp64, this thread's 4 d-columns, 2 s-rows)
#pragma unroll
        for (int i = 0; i < 2; ++i) {
            z4[0] += (double)kr[i].x; z4[1] += (double)kr[i].y;
            z4[2] += (double)kr[i].z; z4[3] += (double)kr[i].w;
        }
        // split + transpose-store to LDS buffer bs (swizzled)
#pragma unroll
        for (int j = 0; j < 4; ++j) {
            const int o = swz(dg + j, sg);   // even -> 4B aligned
            unsigned ph, pl;
            split2((&kr[0].x)[j], (&kr[1].x)[j], ph, pl);
            *(unsigned*)&Kh[bs][o] = ph;
            *(unsigned*)&Kl[bs][o] = pl;
            split2((&vr[0].x)[j], (&vr[1].x)[j], ph, pl);
            *(unsigned*)&Vh[bs][o] = ph;
            *(unsigned*)&Vl[bs][o] = pl;
        }
        wg_barrier();   // LDS-only wait; prefetched global loads stay in flight
        // MFMA: wave owns M rows [rt_*16,+16), cols [ch*32,+32); K-dim 64 = 2 slices
        __builtin_amdgcn_s_setprio(1);
        const int arow = rt_ * 16 + m;
#pragma unroll
        for (int ks = 0; ks < 2; ++ks) {
            const int k0 = ks * 32 + q * 8;
            s8v ahf = ld16(&Kh[bs][swz(arow, k0)]);
            s8v alf = ld16(&Kl[bs][swz(arow, k0)]);
#pragma unroll
            for (int c = 0; c < 2; ++c) {
                const int vrow = (ch * 2 + c) * 16 + m;
                s8v bh = ld16(&Vh[bs][swz(vrow, k0)]);
                s8v bl = ld16(&Vl[bs][swz(vrow, k0)]);
                acc[c] = __builtin_amdgcn_mfma_f32_16x16x32_bf16(ahf, bh, acc[c], 0, 0, 0);
                acc[c] = __builtin_amdgcn_mfma_f32_16x16x32_bf16(ahf, bl, acc[c], 0, 0, 0);
                acc[c] = __builtin_amdgcn_mfma_f32_16x16x32_bf16(alf, bh, acc[c], 0, 0, 0);
            }
        }
        __builtin_amdgcn_s_setprio(0);
    }

    // write partial M (C layout: col=lane&15, row=(lane>>4)*4+reg)
    float* pm = partM + ((long)(head * 8 + chunk) << 12);
#pragma unroll
    for (int c = 0; c < 2; ++c)
#pragma unroll
        for (int r2 = 0; r2 < 4; ++r2)
            pm[(rt_ * 16 + q * 4 + r2) * 64 + (ch * 2 + c) * 16 + m] = acc[c][r2];

    // z reduce: butterfly over the 4 lanes sharing m, then cross-wave via LDS
    // (reuse Kh as scratch — all LDS reads are done; barrier first)
#pragma unroll
    for (int cc = 0; cc < 4; ++cc) {
        z4[cc] += shfl_xor_dbl(z4[cc], 16);
        z4[cc] += shfl_xor_dbl(z4[cc], 32);
    }
    __syncthreads();
    double (*zsw)[16][4] = (double (*)[16][4])&Kh[0][0];   // 4 KB scratch
    if (lane < 16) {
#pragma unroll
        for (int cc = 0; cc < 4; ++cc) zsw[w][lane][cc] = z4[cc];
    }
    __syncthreads();
    if (t < 64) {
        double s = 0.0;
#pragma unroll
        for (int g = 0; g < 8; ++g) s += zsw[g][t >> 2][t & 3];
        partZ[(head * 8 + chunk) * 64 + t] = s;
    }
}

// ---------------- Reduce: sum chunks -> Mt split-bf16 planes + z fp64 ----------------
// grid (4 k-slices, 64 heads). Emits the transposed hi/lo bf16 planes ONCE so
// phase2 needs no LDS staging / re-split (was redundant across 2048 blocks).
__global__ __launch_bounds__(256) void mm_reduce(const float* __restrict__ partM,
                                                 const double* __restrict__ partZ,
                                                 unsigned short* __restrict__ Mthg,
                                                 unsigned short* __restrict__ Mtlg,
                                                 double* __restrict__ zf) {
    __shared__ float Ml[16][68];
    const int b = blockIdx.x, h = blockIdx.y, t = threadIdx.x;
#pragma unroll
    for (int it = 0; it < 4; ++it) {
        const int fl = it * 256 + t;          // 0..1023 within slice
        const int f = b * 1024 + fl;          // flat = k*64 + n
        float s = 0.f;
#pragma unroll
        for (int c = 0; c < 8; ++c) s += partM[(long)(h * 8 + c) * 4096 + f];
        Ml[fl >> 6][fl & 63] = s;
    }
    if (b == 0 && t < 64) {
        double s = 0.0;
#pragma unroll
        for (int c = 0; c < 8; ++c) s += partZ[(h * 8 + c) * 64 + t];
        zf[h * 64 + t] = s;
    }
    __syncthreads();
    // Mt[n][k] = M[k][n], split to bf16 hi/lo: thread t -> row n=t>>2, k = b*16+(t&3)*4..+4
    const int n = t >> 2, kq = (t & 3) * 4;
    uint2 uh, ul;
    split2(Ml[kq + 0][n], Ml[kq + 1][n], uh.x, ul.x);
    split2(Ml[kq + 2][n], Ml[kq + 3][n], uh.y, ul.y);
    const long o = (long)h * 4096 + n * 64 + b * 16 + kq;
    *(uint2*)(Mthg + o) = uh;
    *(uint2*)(Mtlg + o) = ul;
}

// ---------------- Phase 2: out = (Q @ M) / (fp32 den) ----------------
// grid (32 s-blocks, 64 heads), 256 threads, 128 rows/block.
// B fragments straight from global (Mt planes are 1 MB -> L2/L3-hot),
// double-buffered across the ct loop. den from qa registers (fp64 butterfly).
// Only LDS: zl[64]; one raw barrier (Q loads survive it).
__global__ __launch_bounds__(256, 4) void mm_phase2(const float* __restrict__ Qg,
                                                    const unsigned short* __restrict__ Mthg,
                                                    const unsigned short* __restrict__ Mtlg,
                                                    const double* __restrict__ zf,
                                                    float* __restrict__ outg) {
    __shared__ __align__(16) float zl[64];

    const int sb = blockIdx.x, h = blockIdx.y;
    const int t = threadIdx.x, lane = t & 63, w = t >> 6;
    const long hq = (long)h * 4096 * 64;
    const int s0 = sb * 128;
    const int m = lane & 15, q = lane >> 4;

    // ---- A-fragment loads first: pull the Q tile from HBM early ----
    float4 qa[8];
    {
        const float* qr0 = Qg + hq + (long)(s0 + w * 32 + m) * 64;
        const float* qr1 = qr0 + 16 * 64;
#pragma unroll
        for (int i = 0; i < 2; ++i) {
            qa[0 + i] = *(const float4*)(qr0 + q * 8 + 4 * i);
            qa[2 + i] = *(const float4*)(qr0 + 32 + q * 8 + 4 * i);
            qa[4 + i] = *(const float4*)(qr1 + q * 8 + 4 * i);
            qa[6 + i] = *(const float4*)(qr1 + 32 + q * 8 + 4 * i);
        }
    }

    // ---- B-fragment bases + ct=0 prefetch (L2-hot global, 16B/lane) ----
    const unsigned short* mh = Mthg + (long)h * 4096;
    const unsigned short* ml = Mtlg + (long)h * 4096;
    s8v fh0[2], fl0[2], fh1[2], fl1[2];
    auto ldfrag = [&](int ct, int bsel) {
        const unsigned short* r = mh + (ct * 16 + m) * 64 + q * 8;
        const unsigned short* s = ml + (ct * 16 + m) * 64 + q * 8;
        fh0[bsel] = ld16(r);
        fl0[bsel] = ld16(s);
        fh1[bsel] = ld16(r + 32);
        fl1[bsel] = ld16(s + 32);
    };
    ldfrag(0, 0);

    if (t < 64) zl[t] = (float)zf[h * 64 + t];
    wg_barrier();   // zl visible; qa / frag loads stay in flight

    // ---- den from registers: fp32-rounded products (no FMA), exact fp64 sum,
    // then fp32 + EPS. The 4 lanes sharing m jointly hold a full Q row.
    float dv[2][4];
    {
        float zq[16];
        *(float4*)&zq[0]  = *(const float4*)&zl[q * 8];
        *(float4*)&zq[4]  = *(const float4*)&zl[q * 8 + 4];
        *(float4*)&zq[8]  = *(const float4*)&zl[32 + q * 8];
        *(float4*)&zq[12] = *(const float4*)&zl[32 + q * 8 + 4];
        const float* qp0 = (const float*)&qa[0];
        const float* qp1 = (const float*)&qa[4];
        double dp0 = 0.0, dp1 = 0.0;
#pragma unroll
        for (int j = 0; j < 16; ++j) {
            dp0 += (double)__fmul_rn(qp0[j], zq[j]);
            dp1 += (double)__fmul_rn(qp1[j], zq[j]);
        }
        dp0 += shfl_xor_dbl(dp0, 16); dp0 += shfl_xor_dbl(dp0, 32);
        dp1 += shfl_xor_dbl(dp1, 16); dp1 += shfl_xor_dbl(dp1, 32);
        const float den0 = __fadd_rn((float)dp0, EPS);   // row w*32 + m
        const float den1 = __fadd_rn((float)dp1, EPS);   // row w*32 + 16 + m
        // redistribute: output rows are q*4+r2 (+16*rt); lane q*4+r2 holds them
#pragma unroll
        for (int r2 = 0; r2 < 4; ++r2) {
            dv[0][r2] = __shfl(den0, q * 4 + r2, 64);
            dv[1][r2] = __shfl(den1, q * 4 + r2, 64);
        }
    }

    // ---- A fragments (split bf16 hi/lo), both row-tiles ----
    union U8 { s8v v; unsigned u[4]; };
    U8 ah[2][2], al[2][2];
#pragma unroll
    for (int rt = 0; rt < 2; ++rt) {
        const float4* qq = &qa[rt * 4];
        split2(qq[0].x, qq[0].y, ah[rt][0].u[0], al[rt][0].u[0]);
        split2(qq[0].z, qq[0].w, ah[rt][0].u[1], al[rt][0].u[1]);
        split2(qq[1].x, qq[1].y, ah[rt][0].u[2], al[rt][0].u[2]);
        split2(qq[1].z, qq[1].w, ah[rt][0].u[3], al[rt][0].u[3]);
        split2(qq[2].x, qq[2].y, ah[rt][1].u[0], al[rt][1].u[0]);
        split2(qq[2].z, qq[2].w, ah[rt][1].u[1], al[rt][1].u[1]);
        split2(qq[3].x, qq[3].y, ah[rt][1].u[2], al[rt][1].u[2]);
        split2(qq[3].z, qq[3].w, ah[rt][1].u[3], al[rt][1].u[3]);
    }

    // ---- ct loop, B fragments double-buffered from global ----
#pragma unroll
    for (int ct = 0; ct < 4; ++ct) {
        if (ct < 3) ldfrag(ct + 1, (ct + 1) & 1);
        const int cb = ct & 1;
#pragma unroll
        for (int rt = 0; rt < 2; ++rt) {
            f4v acc = (f4v){0.f, 0.f, 0.f, 0.f};
            acc = __builtin_amdgcn_mfma_f32_16x16x32_bf16(ah[rt][0].v, fh0[cb], acc, 0, 0, 0);
            acc = __builtin_amdgcn_mfma_f32_16x16x32_bf16(ah[rt][0].v, fl0[cb], acc, 0, 0, 0);
            acc = __builtin_amdgcn_mfma_f32_16x16x32_bf16(al[rt][0].v, fh0[cb], acc, 0, 0, 0);
            acc = __builtin_amdgcn_mfma_f32_16x16x32_bf16(ah[rt][1].v, fh1[cb], acc, 0, 0, 0);
            acc = __builtin_amdgcn_mfma_f32_16x16x32_bf16(ah[rt][1].v, fl1[cb], acc, 0, 0, 0);
            acc = __builtin_amdgcn_mfma_f32_16x16x32_bf16(al[rt][1].v, fh1[cb], acc, 0, 0, 0);
            const long rb = hq + (long)(s0 + w * 32 + rt * 16 + q * 4) * 64 + ct * 16 + m;
#pragma unroll
            for (int r2 = 0; r2 < 4; ++r2)
                outg[rb + (long)r2 * 64] = __fdiv_rn(acc[r2], dv[rt][r2]);   // IEEE fp32 divide
        }
    }
}

extern "C" void kernel_launch(void* const* d_in, const int* in_sizes, int n_in,
                              void* d_out, int out_size, void* d_ws, size_t ws_size,
                              hipStream_t stream) {
    const float* K = (const float*)d_in[0];
    const float* V = (const float*)d_in[1];
    const float* Q = (const float*)d_in[2];
    float* out = (float*)d_out;

    char* ws = (char*)d_ws;
    float*          partM = (float*)ws;                       // 64*8*4096*4 = 8 MiB
    double*         partZ = (double*)(ws + 8388608);          // 64*8*64*8   = 256 KiB
    unsigned short* Mthg  = (unsigned short*)(ws + 8650752);  // 64*4096*2   = 512 KiB
    unsigned short* Mtlg  = (unsigned short*)(ws + 9175040);  // 64*4096*2   = 512 KiB
    double*         zfin  = (double*)(ws + 9699328);          // 64*64*8     = 32 KiB

    mm_phase1<<<dim3(8, 64), 512, 0, stream>>>(K, V, partM, partZ);
    mm_reduce<<<dim3(4, 64), 256, 0, stream>>>(partM, partZ, Mthg, Mtlg, zfin);
    mm_phase2<<<dim3(32, 64), 256, 0, stream>>>(Q, Mthg, Mtlg, zfin, out);
}